// Round 8
// baseline (211.085 us; speedup 1.0000x reference)
//
#include <hip/hip_runtime.h>

#define DD 128       // EMBED_DIM
#define CAP 48       // per-row slot capacity (Poisson lambda=16; P(deg>=48)~1e-9)
#define OVF_MAX 4096 // overflow list capacity (never expected to fill)

typedef __attribute__((ext_vector_type(8))) short short8;  // 8 bf16 (4 VGPRs)
typedef __attribute__((ext_vector_type(4))) float f32x4;   // MFMA C/D

// Pack two f32 -> packed bf16 pair (round-half-up), lo->[15:0], hi->[31:16].
static __device__ __forceinline__ unsigned pack_bf16_2(float lo, float hi) {
  return __builtin_amdgcn_perm(__float_as_uint(hi) + 0x8000u,
                               __float_as_uint(lo) + 0x8000u, 0x07060302u);
}
static __device__ __forceinline__ unsigned short f2bf(float f) {
  return (unsigned short)((__float_as_uint(f) + 0x8000u) >> 16);
}
static __device__ __forceinline__ float bf2f(unsigned short h) {
  return __uint_as_float((unsigned)h << 16);
}

// ---------------------------------------------------------------------------
// k1: block 0 -> Wt[n][k] = bf16(W[k][n]);  blocks 1.. -> single-pass
// placement of 4B edge INDEX (not 8B payload): pos = atomicAdd(counts[row]).
// Overflow (pos>=CAP) goes to a small global list, applied by k4.
// ---------------------------------------------------------------------------
__global__ __launch_bounds__(256) void k1_transpose_place(
    const float* __restrict__ W, unsigned short* __restrict__ Wtg,
    const int* __restrict__ rows, int* __restrict__ counts,
    int* __restrict__ sidx, int* __restrict__ ovf_cnt, int* __restrict__ ovf,
    int E) {
  const int t = threadIdx.x;
  if (blockIdx.x == 0) {
    const int k0 = (t >> 4) * 8;  // 16 k-groups
    const int n0 = (t & 15) * 8;  // 16 n-groups
    float v[8][8];
#pragma unroll
    for (int kk = 0; kk < 8; ++kk) {
      float4 a = *(const float4*)(W + (k0 + kk) * DD + n0);
      float4 b = *(const float4*)(W + (k0 + kk) * DD + n0 + 4);
      v[kk][0] = a.x; v[kk][1] = a.y; v[kk][2] = a.z; v[kk][3] = a.w;
      v[kk][4] = b.x; v[kk][5] = b.y; v[kk][6] = b.z; v[kk][7] = b.w;
    }
#pragma unroll
    for (int nn = 0; nn < 8; ++nn) {
      uint4 d;
      d.x = pack_bf16_2(v[0][nn], v[1][nn]);
      d.y = pack_bf16_2(v[2][nn], v[3][nn]);
      d.z = pack_bf16_2(v[4][nn], v[5][nn]);
      d.w = pack_bf16_2(v[6][nn], v[7][nn]);
      *(uint4*)(Wtg + (size_t)(n0 + nn) * DD + k0) = d;
    }
  } else {
    const int e = (blockIdx.x - 1) * 256 + t;
    if (e < E) {
      const int row = rows[e];
      const int pos = atomicAdd(&counts[row], 1);
      if (pos < CAP) {
        sidx[(size_t)row * CAP + pos] = e;
      } else {
        const int o = atomicAdd(ovf_cnt, 1);
        if (o < OVF_MAX) ovf[o] = e;
      }
    }
  }
}

// ---------------------------------------------------------------------------
// k2: weighted(bf16) = U @ W via MFMA 16x16x32 bf16. 128 rows/block,
// 4 waves x 32 rows. Wt in LDS, stride 136 (2-way bank aliasing = free).
// do_copy!=0 additionally writes out = U (residual init for fallback path).
// ---------------------------------------------------------------------------
#define WTS 136
__global__ __launch_bounds__(256) void k2_gemm(
    const float* __restrict__ U, const unsigned short* __restrict__ Wtg,
    unsigned short* __restrict__ wb, float* __restrict__ out, int N,
    int do_copy) {
  __shared__ unsigned short Wt[DD][WTS];  // 34.8 KB
  const int t = threadIdx.x;

#pragma unroll
  for (int i = 0; i < 8; ++i) {
    const int s = t + 256 * i;
    const int n = s >> 4;
    const int k0 = (s & 15) * 8;
    uint4 d = *(const uint4*)(Wtg + (size_t)n * DD + k0);
    *(uint4*)(&Wt[n][k0]) = d;
  }

  const int blk_row0 = blockIdx.x * 128;
  if (do_copy) {
    const int nrow = min(128, N - blk_row0);
    const float4* U4 = (const float4*)(U + (size_t)blk_row0 * DD);
    float4* O4 = (float4*)(out + (size_t)blk_row0 * DD);
    for (int i = t; i < nrow * 32; i += 256) O4[i] = U4[i];
  }
  __syncthreads();

  const int w = t >> 6;
  const int lane = t & 63;
  const int m = lane & 15;
  const int quad = lane >> 4;
  const int row_base = blk_row0 + w * 32;

  short8 afrag[2][4];
#pragma unroll
  for (int s = 0; s < 2; ++s) {
    const int r = min(row_base + s * 16 + m, N - 1);
    const float* up = U + (size_t)r * DD + quad * 8;
#pragma unroll
    for (int c = 0; c < 4; ++c) {
      float4 x = *(const float4*)(up + c * 32);
      float4 y = *(const float4*)(up + c * 32 + 4);
      union { unsigned u[4]; short8 v; } fr;
      fr.u[0] = pack_bf16_2(x.x, x.y);
      fr.u[1] = pack_bf16_2(x.z, x.w);
      fr.u[2] = pack_bf16_2(y.x, y.y);
      fr.u[3] = pack_bf16_2(y.z, y.w);
      afrag[s][c] = fr.v;
    }
  }

  f32x4 acc[2][8];
#pragma unroll
  for (int s = 0; s < 2; ++s)
#pragma unroll
    for (int ct = 0; ct < 8; ++ct) acc[s][ct] = (f32x4){0.f, 0.f, 0.f, 0.f};

#pragma unroll
  for (int c = 0; c < 4; ++c) {
#pragma unroll
    for (int ct = 0; ct < 8; ++ct) {
      short8 bfrag = *(const short8*)&Wt[ct * 16 + m][c * 32 + quad * 8];
      acc[0][ct] = __builtin_amdgcn_mfma_f32_16x16x32_bf16(
          afrag[0][c], bfrag, acc[0][ct], 0, 0, 0);
      acc[1][ct] = __builtin_amdgcn_mfma_f32_16x16x32_bf16(
          afrag[1][c], bfrag, acc[1][ct], 0, 0, 0);
    }
  }

  // Epilogue: C/D layout col=lane&15, row=quad*4+reg  [measured m89/m91].
#pragma unroll
  for (int s = 0; s < 2; ++s) {
    const int rb = row_base + s * 16 + quad * 4;
#pragma unroll
    for (int ct = 0; ct < 8; ++ct) {
#pragma unroll
      for (int reg = 0; reg < 4; ++reg) {
        const int r = rb + reg;
        if (r < N) wb[(size_t)r * DD + ct * 16 + m] = f2bf(acc[s][ct][reg]);
      }
    }
  }
}

// ---------------------------------------------------------------------------
// k3: accumulate. One wave per output row; fixed-stride edge-index list;
// wave-uniform cols/vals indirection (broadcast loads); bf16 gather.
// ---------------------------------------------------------------------------
__global__ __launch_bounds__(256) void k3_accumulate(
    const int* __restrict__ counts, const int* __restrict__ sidx,
    const int* __restrict__ cols, const float* __restrict__ vals,
    const unsigned short* __restrict__ wb, const float* __restrict__ U,
    float* __restrict__ out, int N) {
  const int r = blockIdx.x * 4 + (threadIdx.x >> 6);
  if (r >= N) return;
  const int lane = threadIdx.x & 63;

  const ushort2* __restrict__ WB2 = (const ushort2*)wb;
  float2 acc = ((const float2*)U)[(size_t)r * 64 + lane];

  const int cnt = min(counts[r], CAP);
  const int* __restrict__ lst = sidx + (size_t)r * CAP;

  int i = 0;
  for (; i + 8 <= cnt; i += 8) {
    int e[8];
#pragma unroll
    for (int j = 0; j < 8; ++j) e[j] = lst[i + j];
    int c[8];
    float v[8];
#pragma unroll
    for (int j = 0; j < 8; ++j) { c[j] = cols[e[j]]; v[j] = vals[e[j]]; }
    ushort2 a[8];
#pragma unroll
    for (int j = 0; j < 8; ++j) a[j] = WB2[(size_t)c[j] * 64 + lane];
#pragma unroll
    for (int j = 0; j < 8; ++j) {
      acc.x = fmaf(v[j], bf2f(a[j].x), acc.x);
      acc.y = fmaf(v[j], bf2f(a[j].y), acc.y);
    }
  }
  for (; i + 2 <= cnt; i += 2) {
    const int e0 = lst[i], e1 = lst[i + 1];
    const int c0 = cols[e0], c1 = cols[e1];
    const float v0 = vals[e0], v1 = vals[e1];
    const ushort2 a0 = WB2[(size_t)c0 * 64 + lane];
    const ushort2 a1 = WB2[(size_t)c1 * 64 + lane];
    acc.x = fmaf(v0, bf2f(a0.x), acc.x);
    acc.y = fmaf(v0, bf2f(a0.y), acc.y);
    acc.x = fmaf(v1, bf2f(a1.x), acc.x);
    acc.y = fmaf(v1, bf2f(a1.y), acc.y);
  }
  if (i < cnt) {
    const int e0 = lst[i];
    const int c0 = cols[e0];
    const float v0 = vals[e0];
    const ushort2 a0 = WB2[(size_t)c0 * 64 + lane];
    acc.x = fmaf(v0, bf2f(a0.x), acc.x);
    acc.y = fmaf(v0, bf2f(a0.y), acc.y);
  }

  ((float2*)out)[(size_t)r * 64 + lane] = acc;
}

// ---------------------------------------------------------------------------
// k4: apply overflow edges (pos>=CAP in k1) with f32 atomics. Normally 0
// edges -> returns immediately. One wave per edge, grid-stride.
// ---------------------------------------------------------------------------
__global__ __launch_bounds__(256) void k4_overflow(
    const int* __restrict__ ovf_cnt, const int* __restrict__ ovf,
    const int* __restrict__ rows, const int* __restrict__ cols,
    const float* __restrict__ vals, const unsigned short* __restrict__ wb,
    float* __restrict__ out) {
  const int nov = min(*ovf_cnt, OVF_MAX);
  const int wave = (blockIdx.x * 256 + threadIdx.x) >> 6;
  const int nwaves = gridDim.x * 4;
  const int lane = threadIdx.x & 63;
  for (int i = wave; i < nov; i += nwaves) {
    const int e = ovf[i];
    const int row = rows[e];
    const int col = cols[e];
    const float v = vals[e];
    const ushort2 w = ((const ushort2*)wb)[(size_t)col * 64 + lane];
    float* dst = out + (size_t)row * DD + lane * 2;
    unsafeAtomicAdd(dst, v * bf2f(w.x));
    unsafeAtomicAdd(dst + 1, v * bf2f(w.y));
  }
}

// ---------------------------------------------------------------------------
// Fallback scatter (ws too small): f32 atomics into out (= U, via do_copy).
// ---------------------------------------------------------------------------
__global__ __launch_bounds__(256) void scatter_kernel(
    const int* __restrict__ rows, const int* __restrict__ cols,
    const float* __restrict__ vals, const unsigned short* __restrict__ wb,
    float* __restrict__ out, int E) {
  const int tid = blockIdx.x * 256 + threadIdx.x;
  const int e = tid >> 6;
  if (e >= E) return;
  const int lane = tid & 63;

  const int row = rows[e];
  const int col = cols[e];
  const float v = vals[e];

  const ushort2 w = ((const ushort2*)wb)[(size_t)col * 64 + lane];
  float* dst = out + (size_t)row * DD + lane * 2;
  unsafeAtomicAdd(dst, v * bf2f(w.x));
  unsafeAtomicAdd(dst + 1, v * bf2f(w.y));
}

static inline size_t align_up(size_t x, size_t a) { return (x + a - 1) & ~(a - 1); }

extern "C" void kernel_launch(void* const* d_in, const int* in_sizes, int n_in,
                              void* d_out, int out_size, void* d_ws, size_t ws_size,
                              hipStream_t stream) {
  const float* U = (const float*)d_in[0];     // [N, 128]
  const float* W = (const float*)d_in[1];     // [128, 128]
  const int* rows = (const int*)d_in[2];      // [E]
  const int* cols = (const int*)d_in[3];      // [E]
  const float* vals = (const float*)d_in[4];  // [E]
  float* out = (float*)d_out;                 // [N, 128]

  const int N = in_sizes[0] / DD;
  const int E = in_sizes[2];
  const int gemmBlocks = (N + 127) / 128;

  // Workspace layout (16 B aligned segments)
  char* ws = (char*)d_ws;
  size_t off = 0;
  unsigned short* wb = (unsigned short*)(ws + off);
  off = align_up(off + (size_t)N * DD * sizeof(unsigned short), 16);
  unsigned short* Wtg = (unsigned short*)(ws + off);
  off = align_up(off + (size_t)DD * DD * sizeof(unsigned short), 16);
  int* counts = (int*)(ws + off);  // N counts + 1 ovf counter (zeroed together)
  int* ovf_cnt = counts + N;
  off = align_up(off + ((size_t)N + 4) * sizeof(int), 16);
  int* ovf = (int*)(ws + off);
  off = align_up(off + (size_t)OVF_MAX * sizeof(int), 16);
  int* sidx = (int*)(ws + off);
  off = align_up(off + (size_t)N * CAP * sizeof(int), 16);
  const bool fast_ok = (off <= ws_size);

  if (fast_ok) {
    hipMemsetAsync(counts, 0, ((size_t)N + 1) * sizeof(int), stream);
    // k1: transpose (block 0) || single-pass edge-index placement (blocks 1..)
    k1_transpose_place<<<1 + (E + 255) / 256, 256, 0, stream>>>(
        W, Wtg, rows, counts, sidx, ovf_cnt, ovf, E);
    // k2: MFMA gemm (depends only on k1's Wtg)
    k2_gemm<<<gemmBlocks, 256, 0, stream>>>(U, Wtg, wb, out, N, 0);
    // k3: accumulate
    k3_accumulate<<<(N + 3) / 4, 256, 0, stream>>>(counts, sidx, cols, vals,
                                                   wb, U, out, N);
    // k4: apply overflow edges (normally none)
    k4_overflow<<<16, 256, 0, stream>>>(ovf_cnt, ovf, rows, cols, vals, wb, out);
  } else {
    // Fallback: transpose only, gemm w/ residual copy, atomic scatter.
    k1_transpose_place<<<1, 256, 0, stream>>>(W, Wtg, rows, (int*)Wtg,
                                              (int*)Wtg, (int*)Wtg, (int*)Wtg, 0);
    k2_gemm<<<gemmBlocks, 256, 0, stream>>>(U, Wtg, wb, out, N, 1);
    const long long total = (long long)E * 64;
    scatter_kernel<<<(int)((total + 255) / 256), 256, 0, stream>>>(
        rows, cols, vals, wb, out, E);
  }
}

// Round 9
// 189.930 us; speedup vs baseline: 1.1114x; 1.1114x over previous
//
#include <hip/hip_runtime.h>

#define DD 128        // EMBED_DIM
#define CAP 32        // per-row slot capacity (Poisson lambda=16; ~10-20 edges overflow, handled exactly)
#define OVF_MAX 4096  // overflow list capacity
#define EPB 2048      // edges per k1 block (24 KB LDS)
#define PSHIFT 12     // partition = row >> 12 (4096 rows -> 1 MB slot window)

typedef __attribute__((ext_vector_type(8))) short short8;  // 8 bf16 (4 VGPRs)
typedef __attribute__((ext_vector_type(4))) float f32x4;   // MFMA C/D

// Pack two f32 -> packed bf16 pair (round-half-up), lo->[15:0], hi->[31:16].
static __device__ __forceinline__ unsigned pack_bf16_2(float lo, float hi) {
  return __builtin_amdgcn_perm(__float_as_uint(hi) + 0x8000u,
                               __float_as_uint(lo) + 0x8000u, 0x07060302u);
}
static __device__ __forceinline__ unsigned short f2bf(float f) {
  return (unsigned short)((__float_as_uint(f) + 0x8000u) >> 16);
}
static __device__ __forceinline__ float bf2f(unsigned short h) {
  return __uint_as_float((unsigned)h << 16);
}

// ---------------------------------------------------------------------------
// k1: block 0 -> Wt[n][k] = bf16(W[k][n]).  Blocks 1..: stage a 2048-edge
// chunk in LDS, then sweep row-partitions (row>>PSHIFT == p) so that the
// slot region being written at any instant is ~1 MB (L2-resident -> stores
// coalesce into full lines instead of 1 line per store; round-8 lesson).
// ---------------------------------------------------------------------------
__global__ __launch_bounds__(256) void k1_transpose_place(
    const float* __restrict__ W, unsigned short* __restrict__ Wtg,
    const int* __restrict__ rows, const int* __restrict__ cols,
    const float* __restrict__ vals, int* __restrict__ counts,
    int2* __restrict__ spair, int* __restrict__ ovf_cnt, int* __restrict__ ovf,
    int E, int nparts) {
  const int t = threadIdx.x;
  if (blockIdx.x == 0) {
    const int k0 = (t >> 4) * 8;  // 16 k-groups
    const int n0 = (t & 15) * 8;  // 16 n-groups
    float v[8][8];
#pragma unroll
    for (int kk = 0; kk < 8; ++kk) {
      float4 a = *(const float4*)(W + (k0 + kk) * DD + n0);
      float4 b = *(const float4*)(W + (k0 + kk) * DD + n0 + 4);
      v[kk][0] = a.x; v[kk][1] = a.y; v[kk][2] = a.z; v[kk][3] = a.w;
      v[kk][4] = b.x; v[kk][5] = b.y; v[kk][6] = b.z; v[kk][7] = b.w;
    }
#pragma unroll
    for (int nn = 0; nn < 8; ++nn) {
      uint4 d;
      d.x = pack_bf16_2(v[0][nn], v[1][nn]);
      d.y = pack_bf16_2(v[2][nn], v[3][nn]);
      d.z = pack_bf16_2(v[4][nn], v[5][nn]);
      d.w = pack_bf16_2(v[6][nn], v[7][nn]);
      *(uint4*)(Wtg + (size_t)(n0 + nn) * DD + k0) = d;
    }
    return;
  }

  __shared__ int lrow[EPB];
  __shared__ int lcol[EPB];
  __shared__ float lval[EPB];

  const int c0 = (blockIdx.x - 1) * EPB;
  const int n = min(EPB, E - c0);

  for (int i = t; i < n; i += 256) {
    lrow[i] = rows[c0 + i];
    lcol[i] = cols[c0 + i];
    lval[i] = vals[c0 + i];
  }
  __syncthreads();

  for (int p = 0; p < nparts; ++p) {
    for (int i = t; i < n; i += 256) {
      const int r = lrow[i];
      if ((r >> PSHIFT) == p) {
        const int pos = atomicAdd(&counts[r], 1);
        if (pos < CAP) {
          spair[(size_t)r * CAP + pos] =
              make_int2(lcol[i], __float_as_int(lval[i]));
        } else {
          const int o = atomicAdd(ovf_cnt, 1);
          if (o < OVF_MAX) ovf[o] = c0 + i;
        }
      }
    }
  }
}

// ---------------------------------------------------------------------------
// k2: weighted(bf16) = U @ W via MFMA 16x16x32 bf16. 128 rows/block,
// 4 waves x 32 rows. Wt in LDS, stride 136 (2-way bank aliasing = free).
// do_copy!=0 additionally writes out = U (residual init for fallback path).
// ---------------------------------------------------------------------------
#define WTS 136
__global__ __launch_bounds__(256) void k2_gemm(
    const float* __restrict__ U, const unsigned short* __restrict__ Wtg,
    unsigned short* __restrict__ wb, float* __restrict__ out, int N,
    int do_copy) {
  __shared__ unsigned short Wt[DD][WTS];  // 34.8 KB
  const int t = threadIdx.x;

#pragma unroll
  for (int i = 0; i < 8; ++i) {
    const int s = t + 256 * i;
    const int n = s >> 4;
    const int k0 = (s & 15) * 8;
    uint4 d = *(const uint4*)(Wtg + (size_t)n * DD + k0);
    *(uint4*)(&Wt[n][k0]) = d;
  }

  const int blk_row0 = blockIdx.x * 128;
  if (do_copy) {
    const int nrow = min(128, N - blk_row0);
    const float4* U4 = (const float4*)(U + (size_t)blk_row0 * DD);
    float4* O4 = (float4*)(out + (size_t)blk_row0 * DD);
    for (int i = t; i < nrow * 32; i += 256) O4[i] = U4[i];
  }
  __syncthreads();

  const int w = t >> 6;
  const int lane = t & 63;
  const int m = lane & 15;
  const int quad = lane >> 4;
  const int row_base = blk_row0 + w * 32;

  short8 afrag[2][4];
#pragma unroll
  for (int s = 0; s < 2; ++s) {
    const int r = min(row_base + s * 16 + m, N - 1);
    const float* up = U + (size_t)r * DD + quad * 8;
#pragma unroll
    for (int c = 0; c < 4; ++c) {
      float4 x = *(const float4*)(up + c * 32);
      float4 y = *(const float4*)(up + c * 32 + 4);
      union { unsigned u[4]; short8 v; } fr;
      fr.u[0] = pack_bf16_2(x.x, x.y);
      fr.u[1] = pack_bf16_2(x.z, x.w);
      fr.u[2] = pack_bf16_2(y.x, y.y);
      fr.u[3] = pack_bf16_2(y.z, y.w);
      afrag[s][c] = fr.v;
    }
  }

  f32x4 acc[2][8];
#pragma unroll
  for (int s = 0; s < 2; ++s)
#pragma unroll
    for (int ct = 0; ct < 8; ++ct) acc[s][ct] = (f32x4){0.f, 0.f, 0.f, 0.f};

#pragma unroll
  for (int c = 0; c < 4; ++c) {
#pragma unroll
    for (int ct = 0; ct < 8; ++ct) {
      short8 bfrag = *(const short8*)&Wt[ct * 16 + m][c * 32 + quad * 8];
      acc[0][ct] = __builtin_amdgcn_mfma_f32_16x16x32_bf16(
          afrag[0][c], bfrag, acc[0][ct], 0, 0, 0);
      acc[1][ct] = __builtin_amdgcn_mfma_f32_16x16x32_bf16(
          afrag[1][c], bfrag, acc[1][ct], 0, 0, 0);
    }
  }

  // Epilogue: C/D layout col=lane&15, row=quad*4+reg  [measured m89/m91].
#pragma unroll
  for (int s = 0; s < 2; ++s) {
    const int rb = row_base + s * 16 + quad * 4;
#pragma unroll
    for (int ct = 0; ct < 8; ++ct) {
#pragma unroll
      for (int reg = 0; reg < 4; ++reg) {
        const int r = rb + reg;
        if (r < N) wb[(size_t)r * DD + ct * 16 + m] = f2bf(acc[s][ct][reg]);
      }
    }
  }
}

// ---------------------------------------------------------------------------
// k3: accumulate. One wave per output row; fixed-stride (col,val) slots;
// bf16 gather, unroll-8. Rows with cnt>CAP additionally scan the tiny
// overflow list inline (exact; ~10 waves ever take this path).
// ---------------------------------------------------------------------------
__global__ __launch_bounds__(256) void k3_accumulate(
    const int* __restrict__ counts, const int2* __restrict__ spair,
    const unsigned short* __restrict__ wb, const float* __restrict__ U,
    const int* __restrict__ rows, const int* __restrict__ cols,
    const float* __restrict__ vals, const int* __restrict__ ovf_cnt,
    const int* __restrict__ ovf, float* __restrict__ out, int N) {
  const int r = blockIdx.x * 4 + (threadIdx.x >> 6);
  if (r >= N) return;
  const int lane = threadIdx.x & 63;

  const ushort2* __restrict__ WB2 = (const ushort2*)wb;
  float2 acc = ((const float2*)U)[(size_t)r * 64 + lane];

  const int cnt_raw = counts[r];
  const int cnt = min(cnt_raw, CAP);
  const int2* __restrict__ lst = spair + (size_t)r * CAP;

  int i = 0;
  for (; i + 8 <= cnt; i += 8) {
    int2 p[8];
#pragma unroll
    for (int j = 0; j < 8; ++j) p[j] = lst[i + j];
    ushort2 a[8];
#pragma unroll
    for (int j = 0; j < 8; ++j) a[j] = WB2[(size_t)p[j].x * 64 + lane];
#pragma unroll
    for (int j = 0; j < 8; ++j) {
      const float v = __int_as_float(p[j].y);
      acc.x = fmaf(v, bf2f(a[j].x), acc.x);
      acc.y = fmaf(v, bf2f(a[j].y), acc.y);
    }
  }
  for (; i + 2 <= cnt; i += 2) {
    const int2 p0 = lst[i];
    const int2 p1 = lst[i + 1];
    const ushort2 a0 = WB2[(size_t)p0.x * 64 + lane];
    const ushort2 a1 = WB2[(size_t)p1.x * 64 + lane];
    const float v0 = __int_as_float(p0.y);
    const float v1 = __int_as_float(p1.y);
    acc.x = fmaf(v0, bf2f(a0.x), acc.x);
    acc.y = fmaf(v0, bf2f(a0.y), acc.y);
    acc.x = fmaf(v1, bf2f(a1.x), acc.x);
    acc.y = fmaf(v1, bf2f(a1.y), acc.y);
  }
  if (i < cnt) {
    const int2 p0 = lst[i];
    const ushort2 a0 = WB2[(size_t)p0.x * 64 + lane];
    const float v0 = __int_as_float(p0.y);
    acc.x = fmaf(v0, bf2f(a0.x), acc.x);
    acc.y = fmaf(v0, bf2f(a0.y), acc.y);
  }

  if (cnt_raw > CAP) {  // rare exact-overflow path
    const int nov = min(*ovf_cnt, OVF_MAX);
    for (int o = 0; o < nov; ++o) {
      const int e = ovf[o];
      if (rows[e] == r) {
        const float v = vals[e];
        const ushort2 a = WB2[(size_t)cols[e] * 64 + lane];
        acc.x = fmaf(v, bf2f(a.x), acc.x);
        acc.y = fmaf(v, bf2f(a.y), acc.y);
      }
    }
  }

  ((float2*)out)[(size_t)r * 64 + lane] = acc;
}

// ---------------------------------------------------------------------------
// Fallback scatter (ws too small): f32 atomics into out (= U, via do_copy).
// ---------------------------------------------------------------------------
__global__ __launch_bounds__(256) void scatter_kernel(
    const int* __restrict__ rows, const int* __restrict__ cols,
    const float* __restrict__ vals, const unsigned short* __restrict__ wb,
    float* __restrict__ out, int E) {
  const int tid = blockIdx.x * 256 + threadIdx.x;
  const int e = tid >> 6;
  if (e >= E) return;
  const int lane = tid & 63;

  const int row = rows[e];
  const int col = cols[e];
  const float v = vals[e];

  const ushort2 w = ((const ushort2*)wb)[(size_t)col * 64 + lane];
  float* dst = out + (size_t)row * DD + lane * 2;
  unsafeAtomicAdd(dst, v * bf2f(w.x));
  unsafeAtomicAdd(dst + 1, v * bf2f(w.y));
}

static inline size_t align_up(size_t x, size_t a) { return (x + a - 1) & ~(a - 1); }

extern "C" void kernel_launch(void* const* d_in, const int* in_sizes, int n_in,
                              void* d_out, int out_size, void* d_ws, size_t ws_size,
                              hipStream_t stream) {
  const float* U = (const float*)d_in[0];     // [N, 128]
  const float* W = (const float*)d_in[1];     // [128, 128]
  const int* rows = (const int*)d_in[2];      // [E]
  const int* cols = (const int*)d_in[3];      // [E]
  const float* vals = (const float*)d_in[4];  // [E]
  float* out = (float*)d_out;                 // [N, 128]

  const int N = in_sizes[0] / DD;
  const int E = in_sizes[2];
  const int gemmBlocks = (N + 127) / 128;
  const int nparts = (N + (1 << PSHIFT) - 1) >> PSHIFT;
  const int CPB = (E + EPB - 1) / EPB;

  // Workspace layout (16 B aligned segments)
  char* ws = (char*)d_ws;
  size_t off = 0;
  unsigned short* wb = (unsigned short*)(ws + off);
  off = align_up(off + (size_t)N * DD * sizeof(unsigned short), 16);
  unsigned short* Wtg = (unsigned short*)(ws + off);
  off = align_up(off + (size_t)DD * DD * sizeof(unsigned short), 16);
  int* counts = (int*)(ws + off);  // N counts + ovf counter (zeroed together)
  int* ovf_cnt = counts + N;
  off = align_up(off + ((size_t)N + 4) * sizeof(int), 16);
  int* ovf = (int*)(ws + off);
  off = align_up(off + (size_t)OVF_MAX * sizeof(int), 16);
  int2* spair = (int2*)(ws + off);
  off = align_up(off + (size_t)N * CAP * sizeof(int2), 16);
  const bool fast_ok = (off <= ws_size);

  if (fast_ok) {
    hipMemsetAsync(counts, 0, ((size_t)N + 1) * sizeof(int), stream);
    // k1: transpose (block 0) || partition-swept placement (blocks 1..)
    k1_transpose_place<<<1 + CPB, 256, 0, stream>>>(
        W, Wtg, rows, cols, vals, counts, spair, ovf_cnt, ovf, E, nparts);
    // k2: MFMA gemm (depends only on k1's Wtg)
    k2_gemm<<<gemmBlocks, 256, 0, stream>>>(U, Wtg, wb, out, N, 0);
    // k3: accumulate (+ inline exact overflow handling)
    k3_accumulate<<<(N + 3) / 4, 256, 0, stream>>>(
        counts, spair, wb, U, rows, cols, vals, ovf_cnt, ovf, out, N);
  } else {
    // Fallback: transpose only, gemm w/ residual copy, atomic scatter.
    k1_transpose_place<<<1, 256, 0, stream>>>(W, Wtg, rows, cols, vals,
                                              (int*)Wtg, (int2*)Wtg, (int*)Wtg,
                                              (int*)Wtg, 0, 0);
    k2_gemm<<<gemmBlocks, 256, 0, stream>>>(U, Wtg, wb, out, N, 1);
    const long long total = (long long)E * 64;
    scatter_kernel<<<(int)((total + 255) / 256), 256, 0, stream>>>(
        rows, cols, vals, wb, out, E);
  }
}

// Round 10
// 184.595 us; speedup vs baseline: 1.1435x; 1.0289x over previous
//
#include <hip/hip_runtime.h>

#define DD 128        // EMBED_DIM
#define CAP 32        // per-row slot capacity (Poisson lambda=16; overflow handled exactly)
#define OVF_MAX 4096  // overflow list capacity
#define EPB 2048      // edges per staged chunk (24 KB LDS)
#define JMAX 128      // chunk-stride per group; placement blocks = 8*JMAX

typedef __attribute__((ext_vector_type(8))) short short8;  // 8 bf16 (4 VGPRs)
typedef __attribute__((ext_vector_type(4))) float f32x4;   // MFMA C/D

// Pack two f32 -> packed bf16 pair (round-half-up), lo->[15:0], hi->[31:16].
static __device__ __forceinline__ unsigned pack_bf16_2(float lo, float hi) {
  return __builtin_amdgcn_perm(__float_as_uint(hi) + 0x8000u,
                               __float_as_uint(lo) + 0x8000u, 0x07060302u);
}
static __device__ __forceinline__ unsigned short f2bf(float f) {
  return (unsigned short)((__float_as_uint(f) + 0x8000u) >> 16);
}
static __device__ __forceinline__ float bf2f(unsigned short h) {
  return __uint_as_float((unsigned)h << 16);
}

// ---------------------------------------------------------------------------
// k1: block 0 -> Wt[n][k] = bf16(W[k][n]).  Placement blocks b=blockIdx-1:
// group g = b&7 owns rows [g*rpg,(g+1)*rpg). With round-robin block->XCD
// dispatch, all stores into group g's 1.6 MB spair region come from ONE XCD,
// so its L2 merges the ~8 stores/line into a single writeback (round-8/9
// lesson: per-XCD L2s write back dirty sectors independently; cross-XCD
// line sharing forces ~1 writeback per store). Edge chunks are re-read by
// all 8 groups via nontemporal loads (L3-served, no L2 pollution).
// Correctness never depends on the XCD mapping -- only locality does.
// ---------------------------------------------------------------------------
__global__ __launch_bounds__(256) void k1_transpose_place(
    const float* __restrict__ W, unsigned short* __restrict__ Wtg,
    const int* __restrict__ rows, const int* __restrict__ cols,
    const float* __restrict__ vals, int* __restrict__ counts,
    int2* __restrict__ spair, int* __restrict__ ovf_cnt, int* __restrict__ ovf,
    int E, int nchunks, int rpg, int N) {
  const int t = threadIdx.x;
  if (blockIdx.x == 0) {
    const int k0 = (t >> 4) * 8;  // 16 k-groups
    const int n0 = (t & 15) * 8;  // 16 n-groups
    float v[8][8];
#pragma unroll
    for (int kk = 0; kk < 8; ++kk) {
      float4 a = *(const float4*)(W + (k0 + kk) * DD + n0);
      float4 b = *(const float4*)(W + (k0 + kk) * DD + n0 + 4);
      v[kk][0] = a.x; v[kk][1] = a.y; v[kk][2] = a.z; v[kk][3] = a.w;
      v[kk][4] = b.x; v[kk][5] = b.y; v[kk][6] = b.z; v[kk][7] = b.w;
    }
#pragma unroll
    for (int nn = 0; nn < 8; ++nn) {
      uint4 d;
      d.x = pack_bf16_2(v[0][nn], v[1][nn]);
      d.y = pack_bf16_2(v[2][nn], v[3][nn]);
      d.z = pack_bf16_2(v[4][nn], v[5][nn]);
      d.w = pack_bf16_2(v[6][nn], v[7][nn]);
      *(uint4*)(Wtg + (size_t)(n0 + nn) * DD + k0) = d;
    }
    return;
  }

  const int b = blockIdx.x - 1;
  const int g = b & 7;        // row-group == XCD proxy (round-robin dispatch)
  const int j0 = b >> 3;      // starting chunk index
  const int rlo = g * rpg;
  const int rhi = min(rlo + rpg, N);

  __shared__ int lrow[EPB];
  __shared__ int lcol[EPB];
  __shared__ float lval[EPB];

  for (int c = j0; c < nchunks; c += JMAX) {
    const int c0 = c * EPB;
    const int n = min(EPB, E - c0);
    __syncthreads();  // LDS reuse guard
    for (int i = t; i < n; i += 256) {
      lrow[i] = __builtin_nontemporal_load(rows + c0 + i);
      lcol[i] = __builtin_nontemporal_load(cols + c0 + i);
      lval[i] = __builtin_nontemporal_load(vals + c0 + i);
    }
    __syncthreads();
    for (int i = t; i < n; i += 256) {
      const int r = lrow[i];
      if (r >= rlo && r < rhi) {
        const int pos = atomicAdd(&counts[r], 1);
        if (pos < CAP) {
          spair[(size_t)r * CAP + pos] =
              make_int2(lcol[i], __float_as_int(lval[i]));
        } else {
          const int o = atomicAdd(ovf_cnt, 1);
          if (o < OVF_MAX) ovf[o] = c0 + i;
        }
      }
    }
  }
}

// ---------------------------------------------------------------------------
// k2: weighted(bf16) = U @ W via MFMA 16x16x32 bf16. 128 rows/block,
// 4 waves x 32 rows. Wt in LDS, stride 136 (2-way bank aliasing = free).
// do_copy!=0 additionally writes out = U (residual init for fallback path).
// ---------------------------------------------------------------------------
#define WTS 136
__global__ __launch_bounds__(256) void k2_gemm(
    const float* __restrict__ U, const unsigned short* __restrict__ Wtg,
    unsigned short* __restrict__ wb, float* __restrict__ out, int N,
    int do_copy) {
  __shared__ unsigned short Wt[DD][WTS];  // 34.8 KB
  const int t = threadIdx.x;

#pragma unroll
  for (int i = 0; i < 8; ++i) {
    const int s = t + 256 * i;
    const int n = s >> 4;
    const int k0 = (s & 15) * 8;
    uint4 d = *(const uint4*)(Wtg + (size_t)n * DD + k0);
    *(uint4*)(&Wt[n][k0]) = d;
  }

  const int blk_row0 = blockIdx.x * 128;
  if (do_copy) {
    const int nrow = min(128, N - blk_row0);
    const float4* U4 = (const float4*)(U + (size_t)blk_row0 * DD);
    float4* O4 = (float4*)(out + (size_t)blk_row0 * DD);
    for (int i = t; i < nrow * 32; i += 256) O4[i] = U4[i];
  }
  __syncthreads();

  const int w = t >> 6;
  const int lane = t & 63;
  const int m = lane & 15;
  const int quad = lane >> 4;
  const int row_base = blk_row0 + w * 32;

  short8 afrag[2][4];
#pragma unroll
  for (int s = 0; s < 2; ++s) {
    const int r = min(row_base + s * 16 + m, N - 1);
    const float* up = U + (size_t)r * DD + quad * 8;
#pragma unroll
    for (int c = 0; c < 4; ++c) {
      float4 x = *(const float4*)(up + c * 32);
      float4 y = *(const float4*)(up + c * 32 + 4);
      union { unsigned u[4]; short8 v; } fr;
      fr.u[0] = pack_bf16_2(x.x, x.y);
      fr.u[1] = pack_bf16_2(x.z, x.w);
      fr.u[2] = pack_bf16_2(y.x, y.y);
      fr.u[3] = pack_bf16_2(y.z, y.w);
      afrag[s][c] = fr.v;
    }
  }

  f32x4 acc[2][8];
#pragma unroll
  for (int s = 0; s < 2; ++s)
#pragma unroll
    for (int ct = 0; ct < 8; ++ct) acc[s][ct] = (f32x4){0.f, 0.f, 0.f, 0.f};

#pragma unroll
  for (int c = 0; c < 4; ++c) {
#pragma unroll
    for (int ct = 0; ct < 8; ++ct) {
      short8 bfrag = *(const short8*)&Wt[ct * 16 + m][c * 32 + quad * 8];
      acc[0][ct] = __builtin_amdgcn_mfma_f32_16x16x32_bf16(
          afrag[0][c], bfrag, acc[0][ct], 0, 0, 0);
      acc[1][ct] = __builtin_amdgcn_mfma_f32_16x16x32_bf16(
          afrag[1][c], bfrag, acc[1][ct], 0, 0, 0);
    }
  }

  // Epilogue: C/D layout col=lane&15, row=quad*4+reg  [measured m89/m91].
#pragma unroll
  for (int s = 0; s < 2; ++s) {
    const int rb = row_base + s * 16 + quad * 4;
#pragma unroll
    for (int ct = 0; ct < 8; ++ct) {
#pragma unroll
      for (int reg = 0; reg < 4; ++reg) {
        const int r = rb + reg;
        if (r < N) wb[(size_t)r * DD + ct * 16 + m] = f2bf(acc[s][ct][reg]);
      }
    }
  }
}

// ---------------------------------------------------------------------------
// k3: accumulate. One wave per output row; fixed-stride (col,val) slots;
// bf16 gather, unroll-8. Rows with cnt>CAP additionally scan the tiny
// overflow list inline (exact; ~10 waves ever take this path).
// ---------------------------------------------------------------------------
__global__ __launch_bounds__(256) void k3_accumulate(
    const int* __restrict__ counts, const int2* __restrict__ spair,
    const unsigned short* __restrict__ wb, const float* __restrict__ U,
    const int* __restrict__ rows, const int* __restrict__ cols,
    const float* __restrict__ vals, const int* __restrict__ ovf_cnt,
    const int* __restrict__ ovf, float* __restrict__ out, int N) {
  const int r = blockIdx.x * 4 + (threadIdx.x >> 6);
  if (r >= N) return;
  const int lane = threadIdx.x & 63;

  const ushort2* __restrict__ WB2 = (const ushort2*)wb;
  float2 acc = ((const float2*)U)[(size_t)r * 64 + lane];

  const int cnt_raw = counts[r];
  const int cnt = min(cnt_raw, CAP);
  const int2* __restrict__ lst = spair + (size_t)r * CAP;

  int i = 0;
  for (; i + 8 <= cnt; i += 8) {
    int2 p[8];
#pragma unroll
    for (int j = 0; j < 8; ++j) p[j] = lst[i + j];
    ushort2 a[8];
#pragma unroll
    for (int j = 0; j < 8; ++j) a[j] = WB2[(size_t)p[j].x * 64 + lane];
#pragma unroll
    for (int j = 0; j < 8; ++j) {
      const float v = __int_as_float(p[j].y);
      acc.x = fmaf(v, bf2f(a[j].x), acc.x);
      acc.y = fmaf(v, bf2f(a[j].y), acc.y);
    }
  }
  for (; i + 2 <= cnt; i += 2) {
    const int2 p0 = lst[i];
    const int2 p1 = lst[i + 1];
    const ushort2 a0 = WB2[(size_t)p0.x * 64 + lane];
    const ushort2 a1 = WB2[(size_t)p1.x * 64 + lane];
    const float v0 = __int_as_float(p0.y);
    const float v1 = __int_as_float(p1.y);
    acc.x = fmaf(v0, bf2f(a0.x), acc.x);
    acc.y = fmaf(v0, bf2f(a0.y), acc.y);
    acc.x = fmaf(v1, bf2f(a1.x), acc.x);
    acc.y = fmaf(v1, bf2f(a1.y), acc.y);
  }
  if (i < cnt) {
    const int2 p0 = lst[i];
    const ushort2 a0 = WB2[(size_t)p0.x * 64 + lane];
    const float v0 = __int_as_float(p0.y);
    acc.x = fmaf(v0, bf2f(a0.x), acc.x);
    acc.y = fmaf(v0, bf2f(a0.y), acc.y);
  }

  if (cnt_raw > CAP) {  // rare exact-overflow path
    const int nov = min(*ovf_cnt, OVF_MAX);
    for (int o = 0; o < nov; ++o) {
      const int e = ovf[o];
      if (rows[e] == r) {
        const float v = vals[e];
        const ushort2 a = WB2[(size_t)cols[e] * 64 + lane];
        acc.x = fmaf(v, bf2f(a.x), acc.x);
        acc.y = fmaf(v, bf2f(a.y), acc.y);
      }
    }
  }

  ((float2*)out)[(size_t)r * 64 + lane] = acc;
}

// ---------------------------------------------------------------------------
// Fallback scatter (ws too small): f32 atomics into out (= U, via do_copy).
// ---------------------------------------------------------------------------
__global__ __launch_bounds__(256) void scatter_kernel(
    const int* __restrict__ rows, const int* __restrict__ cols,
    const float* __restrict__ vals, const unsigned short* __restrict__ wb,
    float* __restrict__ out, int E) {
  const int tid = blockIdx.x * 256 + threadIdx.x;
  const int e = tid >> 6;
  if (e >= E) return;
  const int lane = tid & 63;

  const int row = rows[e];
  const int col = cols[e];
  const float v = vals[e];

  const ushort2 w = ((const ushort2*)wb)[(size_t)col * 64 + lane];
  float* dst = out + (size_t)row * DD + lane * 2;
  unsafeAtomicAdd(dst, v * bf2f(w.x));
  unsafeAtomicAdd(dst + 1, v * bf2f(w.y));
}

static inline size_t align_up(size_t x, size_t a) { return (x + a - 1) & ~(a - 1); }

extern "C" void kernel_launch(void* const* d_in, const int* in_sizes, int n_in,
                              void* d_out, int out_size, void* d_ws, size_t ws_size,
                              hipStream_t stream) {
  const float* U = (const float*)d_in[0];     // [N, 128]
  const float* W = (const float*)d_in[1];     // [128, 128]
  const int* rows = (const int*)d_in[2];      // [E]
  const int* cols = (const int*)d_in[3];      // [E]
  const float* vals = (const float*)d_in[4];  // [E]
  float* out = (float*)d_out;                 // [N, 128]

  const int N = in_sizes[0] / DD;
  const int E = in_sizes[2];
  const int gemmBlocks = (N + 127) / 128;
  const int nchunks = (E + EPB - 1) / EPB;
  const int rpg = (N + 7) / 8;  // rows per group

  // Workspace layout (16 B aligned segments)
  char* ws = (char*)d_ws;
  size_t off = 0;
  unsigned short* wb = (unsigned short*)(ws + off);
  off = align_up(off + (size_t)N * DD * sizeof(unsigned short), 16);
  unsigned short* Wtg = (unsigned short*)(ws + off);
  off = align_up(off + (size_t)DD * DD * sizeof(unsigned short), 16);
  int* counts = (int*)(ws + off);  // N counts + ovf counter (zeroed together)
  int* ovf_cnt = counts + N;
  off = align_up(off + ((size_t)N + 4) * sizeof(int), 16);
  int* ovf = (int*)(ws + off);
  off = align_up(off + (size_t)OVF_MAX * sizeof(int), 16);
  int2* spair = (int2*)(ws + off);
  off = align_up(off + (size_t)N * CAP * sizeof(int2), 16);
  const bool fast_ok = (off <= ws_size);

  if (fast_ok) {
    hipMemsetAsync(counts, 0, ((size_t)N + 1) * sizeof(int), stream);
    // k1: transpose (block 0) || XCD-local group placement (blocks 1..)
    k1_transpose_place<<<1 + 8 * JMAX, 256, 0, stream>>>(
        W, Wtg, rows, cols, vals, counts, spair, ovf_cnt, ovf, E, nchunks,
        rpg, N);
    // k2: MFMA gemm (depends only on k1's Wtg)
    k2_gemm<<<gemmBlocks, 256, 0, stream>>>(U, Wtg, wb, out, N, 0);
    // k3: accumulate (+ inline exact overflow handling)
    k3_accumulate<<<(N + 3) / 4, 256, 0, stream>>>(
        counts, spair, wb, U, rows, cols, vals, ovf_cnt, ovf, out, N);
  } else {
    // Fallback: transpose only, gemm w/ residual copy, atomic scatter.
    k1_transpose_place<<<1, 256, 0, stream>>>(W, Wtg, rows, cols, vals,
                                              (int*)Wtg, (int2*)Wtg, (int*)Wtg,
                                              (int*)Wtg, 0, 0, rpg, N);
    k2_gemm<<<gemmBlocks, 256, 0, stream>>>(U, Wtg, wb, out, N, 1);
    const long long total = (long long)E * 64;
    scatter_kernel<<<(int)((total + 255) / 256), 256, 0, stream>>>(
        rows, cols, vals, wb, out, E);
  }
}

// Round 11
// 164.215 us; speedup vs baseline: 1.2854x; 1.1241x over previous
//
#include <hip/hip_runtime.h>

#define DD 128         // EMBED_DIM
#define CAP 32         // per-row slot capacity (overflow handled exactly)
#define OVF_MAX 4096   // overflow list capacity (int4 entries)
#define EPB 2048       // edges per p1 chunk
#define BSHIFT 10      // bucket = row >> 10 (1024 rows/bucket)
#define NBKT_MAX 64
#define BCAP 24576     // bucket capacity (lambda~16.3K, +64 sigma)

typedef __attribute__((ext_vector_type(8))) short short8;  // 8 bf16 (4 VGPRs)
typedef __attribute__((ext_vector_type(4))) float f32x4;   // MFMA C/D

static __device__ __forceinline__ unsigned pack_bf16_2(float lo, float hi) {
  return __builtin_amdgcn_perm(__float_as_uint(hi) + 0x8000u,
                               __float_as_uint(lo) + 0x8000u, 0x07060302u);
}
static __device__ __forceinline__ unsigned short f2bf(float f) {
  return (unsigned short)((__float_as_uint(f) + 0x8000u) >> 16);
}
static __device__ __forceinline__ float bf2f(unsigned short h) {
  return __uint_as_float((unsigned)h << 16);
}

// ---------------------------------------------------------------------------
// p1: block 0 -> Wt[n][k] = bf16(W[k][n]) transpose. Blocks 1..: bucket
// scatter. Per 2048-edge chunk: LDS histogram by row>>10, one global
// atomicAdd per (block,bucket) reserves a contiguous run, edges written as
// dense 8 B runs (~40 consecutive -> full-line writebacks, single XCD).
// Rounds 7-10 lesson: random 8 B stores cost a full line each; only
// contiguous single-owner runs merge.
// ---------------------------------------------------------------------------
__global__ __launch_bounds__(256) void p1_bucket(
    const float* __restrict__ W, unsigned short* __restrict__ Wtg,
    const int* __restrict__ rows, const int* __restrict__ cols,
    const float* __restrict__ vals, int* __restrict__ binctr,
    int2* __restrict__ bucket, int* __restrict__ ovf_cnt,
    int4* __restrict__ ovf, int E, int nbkt) {
  const int t = threadIdx.x;
  if (blockIdx.x == 0) {
    const int k0 = (t >> 4) * 8;
    const int n0 = (t & 15) * 8;
    float v[8][8];
#pragma unroll
    for (int kk = 0; kk < 8; ++kk) {
      float4 a = *(const float4*)(W + (k0 + kk) * DD + n0);
      float4 b = *(const float4*)(W + (k0 + kk) * DD + n0 + 4);
      v[kk][0] = a.x; v[kk][1] = a.y; v[kk][2] = a.z; v[kk][3] = a.w;
      v[kk][4] = b.x; v[kk][5] = b.y; v[kk][6] = b.z; v[kk][7] = b.w;
    }
#pragma unroll
    for (int nn = 0; nn < 8; ++nn) {
      uint4 d;
      d.x = pack_bf16_2(v[0][nn], v[1][nn]);
      d.y = pack_bf16_2(v[2][nn], v[3][nn]);
      d.z = pack_bf16_2(v[4][nn], v[5][nn]);
      d.w = pack_bf16_2(v[6][nn], v[7][nn]);
      *(uint4*)(Wtg + (size_t)(n0 + nn) * DD + k0) = d;
    }
    return;
  }

  __shared__ int lrow[EPB];            // 8 KB
  __shared__ int hist[NBKT_MAX];
  __shared__ int gbase[NBKT_MAX];
  __shared__ int lcur[NBKT_MAX];

  const int c0 = (blockIdx.x - 1) * EPB;
  const int n = min(EPB, E - c0);

  if (t < NBKT_MAX) { hist[t] = 0; lcur[t] = 0; }
  __syncthreads();

  // Pass A: stage rows, histogram by bucket.
  for (int i = t; i < n; i += 256) {
    const int r = rows[c0 + i];
    lrow[i] = r;
    atomicAdd(&hist[r >> BSHIFT], 1);
  }
  __syncthreads();

  // Reserve contiguous runs in each bucket.
  if (t < nbkt && hist[t] > 0) gbase[t] = atomicAdd(&binctr[t], hist[t]);
  __syncthreads();

  // Pass B: place edges into runs (cols/vals re-read coalesced, L2-hot).
  for (int i = t; i < n; i += 256) {
    const int r = lrow[i];
    const int b = r >> BSHIFT;
    const int lpos = atomicAdd(&lcur[b], 1);
    const int idx = gbase[b] + lpos;
    const int col = cols[c0 + i];
    const float v = vals[c0 + i];
    if (idx < BCAP) {
      // pack: bits[31:22] = row&1023, bits[21:0] = col (col < 4M)
      bucket[(size_t)b * BCAP + idx] =
          make_int2(((r & 1023) << 22) | col, __float_as_int(v));
    } else {
      const int o = atomicAdd(ovf_cnt, 1);
      if (o < OVF_MAX) ovf[o] = make_int4(r, col, __float_as_int(v), 0);
    }
  }
}

// ---------------------------------------------------------------------------
// p2k2 fused: blocks [0,nbkt) -> per-bucket placement (LDS slot counters,
// stores confined to a 256 KB block-private window -> full L2 merging; also
// writes counts[] so no big memset). Blocks [nbkt,..) -> MFMA GEMM
// (depends only on p1's Wtg; overlaps with placement on the CUs).
// ---------------------------------------------------------------------------
#define WTS 136
__global__ __launch_bounds__(256) void p2k2_fused(
    const int* __restrict__ binctr, const int2* __restrict__ bucket,
    int* __restrict__ counts, int2* __restrict__ spair,
    int* __restrict__ ovf_cnt, int4* __restrict__ ovf,
    const float* __restrict__ U, const unsigned short* __restrict__ Wtg,
    unsigned short* __restrict__ wb, float* __restrict__ out, int N,
    int nbkt, int do_copy) {
  __shared__ union {
    unsigned short Wt[DD][WTS];  // 34.8 KB (gemm)
    int scnt[1 << BSHIFT];       // 4 KB (placement)
  } sm;
  const int t = threadIdx.x;

  if ((int)blockIdx.x < nbkt) {
    // ---- placement for bucket b ----
    const int b = blockIdx.x;
    const int base = b << BSHIFT;
    const int nrows = min(1 << BSHIFT, N - base);
    for (int i = t; i < (1 << BSHIFT); i += 256) sm.scnt[i] = 0;
    __syncthreads();

    const int nb = min(binctr[b], BCAP);
    const int2* __restrict__ bkt = bucket + (size_t)b * BCAP;
    for (int i = t; i < nb; i += 256) {
      const int2 p = bkt[i];
      const int lr = (unsigned)p.x >> 22;
      const int col = p.x & 0x3FFFFF;
      const int slot = atomicAdd(&sm.scnt[lr], 1);
      if (slot < CAP) {
        spair[(size_t)(base + lr) * CAP + slot] = make_int2(col, p.y);
      } else {
        const int o = atomicAdd(ovf_cnt, 1);
        if (o < OVF_MAX) ovf[o] = make_int4(base + lr, col, p.y, 0);
      }
    }
    __syncthreads();
    for (int i = t; i < nrows; i += 256) counts[base + i] = sm.scnt[i];
    return;
  }

  // ---- GEMM: weighted(bf16) = U @ W, 128 rows/block, 4 waves x 32 rows ----
  const int gb = blockIdx.x - nbkt;
#pragma unroll
  for (int i = 0; i < 8; ++i) {
    const int s = t + 256 * i;
    const int nn = s >> 4;
    const int k0 = (s & 15) * 8;
    uint4 d = *(const uint4*)(Wtg + (size_t)nn * DD + k0);
    *(uint4*)(&sm.Wt[nn][k0]) = d;
  }

  const int blk_row0 = gb * 128;
  if (do_copy) {
    const int nrow = min(128, N - blk_row0);
    const float4* U4 = (const float4*)(U + (size_t)blk_row0 * DD);
    float4* O4 = (float4*)(out + (size_t)blk_row0 * DD);
    for (int i = t; i < nrow * 32; i += 256) O4[i] = U4[i];
  }
  __syncthreads();

  const int w = t >> 6;
  const int lane = t & 63;
  const int m = lane & 15;
  const int quad = lane >> 4;
  const int row_base = blk_row0 + w * 32;

  short8 afrag[2][4];
#pragma unroll
  for (int s = 0; s < 2; ++s) {
    const int r = min(row_base + s * 16 + m, N - 1);
    const float* up = U + (size_t)r * DD + quad * 8;
#pragma unroll
    for (int c = 0; c < 4; ++c) {
      float4 x = *(const float4*)(up + c * 32);
      float4 y = *(const float4*)(up + c * 32 + 4);
      union { unsigned u[4]; short8 v; } fr;
      fr.u[0] = pack_bf16_2(x.x, x.y);
      fr.u[1] = pack_bf16_2(x.z, x.w);
      fr.u[2] = pack_bf16_2(y.x, y.y);
      fr.u[3] = pack_bf16_2(y.z, y.w);
      afrag[s][c] = fr.v;
    }
  }

  f32x4 acc[2][8];
#pragma unroll
  for (int s = 0; s < 2; ++s)
#pragma unroll
    for (int ct = 0; ct < 8; ++ct) acc[s][ct] = (f32x4){0.f, 0.f, 0.f, 0.f};

#pragma unroll
  for (int c = 0; c < 4; ++c) {
#pragma unroll
    for (int ct = 0; ct < 8; ++ct) {
      short8 bfrag = *(const short8*)&sm.Wt[ct * 16 + m][c * 32 + quad * 8];
      acc[0][ct] = __builtin_amdgcn_mfma_f32_16x16x32_bf16(
          afrag[0][c], bfrag, acc[0][ct], 0, 0, 0);
      acc[1][ct] = __builtin_amdgcn_mfma_f32_16x16x32_bf16(
          afrag[1][c], bfrag, acc[1][ct], 0, 0, 0);
    }
  }

  // Epilogue: C/D layout col=lane&15, row=quad*4+reg  [measured m89/m91].
#pragma unroll
  for (int s = 0; s < 2; ++s) {
    const int rb = row_base + s * 16 + quad * 4;
#pragma unroll
    for (int ct = 0; ct < 8; ++ct) {
#pragma unroll
      for (int reg = 0; reg < 4; ++reg) {
        const int r = rb + reg;
        if (r < N) wb[(size_t)r * DD + ct * 16 + m] = f2bf(acc[s][ct][reg]);
      }
    }
  }
}

// ---------------------------------------------------------------------------
// k3: accumulate. One wave per output row; fixed-stride (col,val) slots;
// bf16 gather, unroll-8. Self-contained int4 overflow list (scanned by all
// waves only if non-empty; normally empty).
// ---------------------------------------------------------------------------
__global__ __launch_bounds__(256) void k3_accumulate(
    const int* __restrict__ counts, const int2* __restrict__ spair,
    const unsigned short* __restrict__ wb, const float* __restrict__ U,
    const int* __restrict__ ovf_cnt, const int4* __restrict__ ovf,
    float* __restrict__ out, int N) {
  const int r = blockIdx.x * 4 + (threadIdx.x >> 6);
  if (r >= N) return;
  const int lane = threadIdx.x & 63;

  const ushort2* __restrict__ WB2 = (const ushort2*)wb;
  float2 acc = ((const float2*)U)[(size_t)r * 64 + lane];

  const int cnt = min(counts[r], CAP);
  const int2* __restrict__ lst = spair + (size_t)r * CAP;

  int i = 0;
  for (; i + 8 <= cnt; i += 8) {
    int2 p[8];
#pragma unroll
    for (int j = 0; j < 8; ++j) p[j] = lst[i + j];
    ushort2 a[8];
#pragma unroll
    for (int j = 0; j < 8; ++j) a[j] = WB2[(size_t)p[j].x * 64 + lane];
#pragma unroll
    for (int j = 0; j < 8; ++j) {
      const float v = __int_as_float(p[j].y);
      acc.x = fmaf(v, bf2f(a[j].x), acc.x);
      acc.y = fmaf(v, bf2f(a[j].y), acc.y);
    }
  }
  for (; i + 2 <= cnt; i += 2) {
    const int2 p0 = lst[i];
    const int2 p1 = lst[i + 1];
    const ushort2 a0 = WB2[(size_t)p0.x * 64 + lane];
    const ushort2 a1 = WB2[(size_t)p1.x * 64 + lane];
    const float v0 = __int_as_float(p0.y);
    const float v1 = __int_as_float(p1.y);
    acc.x = fmaf(v0, bf2f(a0.x), acc.x);
    acc.y = fmaf(v0, bf2f(a0.y), acc.y);
    acc.x = fmaf(v1, bf2f(a1.x), acc.x);
    acc.y = fmaf(v1, bf2f(a1.y), acc.y);
  }
  if (i < cnt) {
    const int2 p0 = lst[i];
    const ushort2 a0 = WB2[(size_t)p0.x * 64 + lane];
    const float v0 = __int_as_float(p0.y);
    acc.x = fmaf(v0, bf2f(a0.x), acc.x);
    acc.y = fmaf(v0, bf2f(a0.y), acc.y);
  }

  const int nov = min(*ovf_cnt, OVF_MAX);  // wave-uniform broadcast load
  if (nov > 0) {                            // normally never taken
    for (int o = 0; o < nov; ++o) {
      const int4 e = ovf[o];
      if (e.x == r) {
        const float v = __int_as_float(e.z);
        const ushort2 a = WB2[(size_t)e.y * 64 + lane];
        acc.x = fmaf(v, bf2f(a.x), acc.x);
        acc.y = fmaf(v, bf2f(a.y), acc.y);
      }
    }
  }

  ((float2*)out)[(size_t)r * 64 + lane] = acc;
}

// ---------------------------------------------------------------------------
// Fallback scatter (ws too small): f32 atomics into out (= U, via do_copy).
// ---------------------------------------------------------------------------
__global__ __launch_bounds__(256) void scatter_kernel(
    const int* __restrict__ rows, const int* __restrict__ cols,
    const float* __restrict__ vals, const unsigned short* __restrict__ wb,
    float* __restrict__ out, int E) {
  const int tid = blockIdx.x * 256 + threadIdx.x;
  const int e = tid >> 6;
  if (e >= E) return;
  const int lane = tid & 63;

  const int row = rows[e];
  const int col = cols[e];
  const float v = vals[e];

  const ushort2 w = ((const ushort2*)wb)[(size_t)col * 64 + lane];
  float* dst = out + (size_t)row * DD + lane * 2;
  unsafeAtomicAdd(dst, v * bf2f(w.x));
  unsafeAtomicAdd(dst + 1, v * bf2f(w.y));
}

static inline size_t align_up(size_t x, size_t a) { return (x + a - 1) & ~(a - 1); }

extern "C" void kernel_launch(void* const* d_in, const int* in_sizes, int n_in,
                              void* d_out, int out_size, void* d_ws, size_t ws_size,
                              hipStream_t stream) {
  const float* U = (const float*)d_in[0];     // [N, 128]
  const float* W = (const float*)d_in[1];     // [128, 128]
  const int* rows = (const int*)d_in[2];      // [E]
  const int* cols = (const int*)d_in[3];      // [E]
  const float* vals = (const float*)d_in[4];  // [E]
  float* out = (float*)d_out;                 // [N, 128]

  const int N = in_sizes[0] / DD;
  const int E = in_sizes[2];
  const int gemmBlocks = (N + 127) / 128;
  const int nchunks = (E + EPB - 1) / EPB;
  const int nbkt = (N + (1 << BSHIFT) - 1) >> BSHIFT;  // 49 for N=50000

  // Workspace layout (16 B aligned segments)
  char* ws = (char*)d_ws;
  size_t off = 0;
  unsigned short* wb = (unsigned short*)(ws + off);
  off = align_up(off + (size_t)N * DD * sizeof(unsigned short), 16);
  unsigned short* Wtg = (unsigned short*)(ws + off);
  off = align_up(off + (size_t)DD * DD * sizeof(unsigned short), 16);
  int* counts = (int*)(ws + off);
  off = align_up(off + (size_t)N * sizeof(int), 16);
  int* binctr = (int*)(ws + off);  // NBKT_MAX bins + ovf counter, zeroed together
  int* ovf_cnt = binctr + NBKT_MAX;
  off = align_up(off + (NBKT_MAX + 4) * sizeof(int), 16);
  int4* ovf = (int4*)(ws + off);
  off = align_up(off + (size_t)OVF_MAX * sizeof(int4), 16);
  int2* bucket = (int2*)(ws + off);
  off = align_up(off + (size_t)nbkt * BCAP * sizeof(int2), 16);
  int2* spair = (int2*)(ws + off);
  off = align_up(off + (size_t)N * CAP * sizeof(int2), 16);
  const bool fast_ok = (off <= ws_size) && (nbkt <= NBKT_MAX);

  if (fast_ok) {
    hipMemsetAsync(binctr, 0, (NBKT_MAX + 1) * sizeof(int), stream);  // 260 B
    // p1: transpose (block 0) || bucket scatter (blocks 1..)
    p1_bucket<<<1 + nchunks, 256, 0, stream>>>(
        W, Wtg, rows, cols, vals, binctr, bucket, ovf_cnt, ovf, E, nbkt);
    // p2 (buckets -> spair/counts) || k2 gemm, fused
    p2k2_fused<<<nbkt + gemmBlocks, 256, 0, stream>>>(
        binctr, bucket, counts, spair, ovf_cnt, ovf, U, Wtg, wb, out, N,
        nbkt, 0);
    // k3: accumulate
    k3_accumulate<<<(N + 3) / 4, 256, 0, stream>>>(
        counts, spair, wb, U, ovf_cnt, ovf, out, N);
  } else {
    // Fallback: transpose only, gemm w/ residual copy, atomic scatter.
    p1_bucket<<<1, 256, 0, stream>>>(W, Wtg, rows, cols, vals, (int*)Wtg,
                                     (int2*)Wtg, (int*)Wtg, (int4*)Wtg, 0, 0);
    p2k2_fused<<<gemmBlocks, 256, 0, stream>>>(
        (const int*)Wtg, (const int2*)Wtg, (int*)Wtg, (int2*)Wtg, (int*)Wtg,
        (int4*)Wtg, U, Wtg, wb, out, N, 0, 1);
    const long long total = (long long)E * 64;
    scatter_kernel<<<(int)((total + 255) / 256), 256, 0, stream>>>(
        rows, cols, vals, wb, out, E);
  }
}